// Round 1
// baseline (640.127 us; speedup 1.0000x reference)
//
#include <hip/hip_runtime.h>
#include <hip/hip_fp16.h>

#define N_NODES 100000
#define IN_CH 128
#define OUT_CH 64
#define HID 128
#define N_EDGES 1600000

#define NBUCK 196               // dst >> 9, max 99999>>9 = 195
#define BBLK  512               // binning blocks (2 per CU)
#define CHUNK (N_EDGES / BBLK)  // 3125 edges per binning block
#define NH    (NBUCK * BBLK)    // 100352 histogram entries

// slice-major fp16 feature layout: [8 slices][N_NODES][16 ch]
// slice s is 3.2 MB -> fits one XCD's 4 MB L2 when pinned via blockIdx%8
#define SLICE ((size_t)N_NODES * 16)   // halfs per slice
#define AGG_NPB 128                    // nodes per agg block
#define AGG_NB ((N_NODES + AGG_NPB - 1) / AGG_NPB)  // 782

typedef _Float16 half8 __attribute__((ext_vector_type(8)));
typedef float floatx4 __attribute__((ext_vector_type(4)));

// ---------------- pass 1: per-(bucket,block) histogram (LDS atomics; fully overwrites hist) ----

__global__ __launch_bounds__(256) void k_hist(const int* __restrict__ dst, int* __restrict__ hist) {
    __shared__ int lh[NBUCK];
    int t = threadIdx.x;
    int blk = blockIdx.x;
    if (t < NBUCK) lh[t] = 0;
    __syncthreads();
    int base = blk * CHUNK;
    for (int i = base + t; i < base + CHUNK; i += 256) {
        atomicAdd(&lh[dst[i] >> 9], 1);
    }
    __syncthreads();
    if (t < NBUCK) hist[t * BBLK + blk] = lh[t];
}

// ---------------- hierarchical exclusive scan (hist only) ----------------

#define SCAN_T 1024
__global__ void k_scan_local(const int* __restrict__ in, int* __restrict__ excl,
                             int* __restrict__ bsum, int n) {
    __shared__ int tmp[SCAN_T];
    int t = threadIdx.x;
    int i = blockIdx.x * SCAN_T + t;
    int v = (i < n) ? in[i] : 0;
    tmp[t] = v;
    __syncthreads();
    for (int off = 1; off < SCAN_T; off <<= 1) {
        int u = (t >= off) ? tmp[t - off] : 0;
        __syncthreads();
        tmp[t] += u;
        __syncthreads();
    }
    if (i < n) excl[i] = tmp[t] - v;
    if (t == SCAN_T - 1) bsum[blockIdx.x] = tmp[t];
}

__global__ void k_scan_sums(const int* __restrict__ bsum, int* __restrict__ boff, int nb) {
    __shared__ int tmp[128];
    int t = threadIdx.x;
    int v = (t < nb) ? bsum[t] : 0;
    tmp[t] = v;
    __syncthreads();
    for (int off = 1; off < 128; off <<= 1) {
        int u = (t >= off) ? tmp[t - off] : 0;
        __syncthreads();
        tmp[t] += u;
        __syncthreads();
    }
    if (t < nb) boff[t] = tmp[t] - v;
}

__global__ void k_scan_add1(const int* __restrict__ excl, const int* __restrict__ boff,
                            int* __restrict__ out, int n) {
    int i = blockIdx.x * blockDim.x + threadIdx.x;
    if (i < n) out[i] = excl[i] + boff[i / SCAN_T];
}

// ---------------- pass 2: scatter edges into bucket-partitioned array ----------------

__global__ __launch_bounds__(256) void k_binscatter(const int* __restrict__ src,
                                                    const int* __restrict__ dst,
                                                    const int* __restrict__ off,
                                                    int2* __restrict__ binned) {
    __shared__ int loff[NBUCK];
    int t = threadIdx.x;
    int blk = blockIdx.x;
    if (t < NBUCK) loff[t] = off[t * BBLK + blk];
    __syncthreads();
    int base = blk * CHUNK;
    for (int i = base + t; i < base + CHUNK; i += 256) {
        int d = dst[i];
        int s = src[i];
        int pos = atomicAdd(&loff[d >> 9], 1);
        binned[pos] = make_int2(s, d);
    }
}

// ---------------- pass 3: per-bucket degree/scan/fill entirely in LDS ----------------
// Produces row_start (with sentinel), dinv, csr_src. Zero global atomics.

__global__ __launch_bounds__(256) void k_bucket(const int2* __restrict__ binned,
                                                const int* __restrict__ off,
                                                int* __restrict__ row_start,
                                                float* __restrict__ dinv,
                                                int* __restrict__ csr_src) {
    __shared__ int cnt[512];
    __shared__ int ps[256];
    __shared__ int cur[512];
    int b = blockIdx.x;
    int t = threadIdx.x;
    int start = off[b * BBLK];
    int end = (b + 1 < NBUCK) ? off[(b + 1) * BBLK] : N_EDGES;
    cnt[t] = 0;
    cnt[t + 256] = 0;
    if (b == NBUCK - 1 && t == 0) row_start[N_NODES] = N_EDGES;  // sentinel
    __syncthreads();
    for (int i = start + t; i < end; i += 256) {
        atomicAdd(&cnt[binned[i].y & 511], 1);
    }
    __syncthreads();
    int a0 = cnt[2 * t], a1 = cnt[2 * t + 1];
    ps[t] = a0 + a1;
    __syncthreads();
    for (int o = 1; o < 256; o <<= 1) {
        int u = (t >= o) ? ps[t - o] : 0;
        __syncthreads();
        ps[t] += u;
        __syncthreads();
    }
    int pe = ps[t] - (a0 + a1);
    int e0 = start + pe;
    int e1 = e0 + a0;
    cur[2 * t] = e0;
    cur[2 * t + 1] = e1;
    int node0 = (b << 9) + 2 * t;
    if (node0 < N_NODES) {
        row_start[node0] = e0;
        dinv[node0] = rsqrtf((float)(a0 + 1));
    }
    if (node0 + 1 < N_NODES) {
        row_start[node0 + 1] = e1;
        dinv[node0 + 1] = rsqrtf((float)(a1 + 1));
    }
    __syncthreads();
    for (int i = start + t; i < end; i += 256) {
        int2 e = binned[i];
        int p = atomicAdd(&cur[e.y & 511], 1);
        csr_src[p] = e.x;
    }
}

// ---------------- cast + pre-scale into SLICE-MAJOR layout ----------------
// xs[slice][node][16] = fp16(dinv[node] * x[node][slice*16 + c])

__global__ __launch_bounds__(256) void k_cast_scale(const float* __restrict__ in,
                                                    const float* __restrict__ dinv,
                                                    __half* __restrict__ out) {
    int i = blockIdx.x * blockDim.x + threadIdx.x;  // over float4 groups, 32 per row
    if (i < N_NODES * 32) {
        float4 v = ((const float4*)in)[i];
        int node = i >> 5, ch4 = i & 31;
        float d = dinv[node];
        // half2 units: slice stride = N_NODES*8, node stride = 8
        size_t o = (size_t)(ch4 >> 2) * (SLICE / 2) + (size_t)node * 8 + (size_t)(ch4 & 3) * 2;
        ((__half2*)out)[o]     = __floats2half2_rn(d * v.x, d * v.y);
        ((__half2*)out)[o + 1] = __floats2half2_rn(d * v.z, d * v.w);
    }
}

// ---------------- weight prep: fp16 transposed (col-major) for MFMA B-fragments --------
// W1t[n][k] = W1[k][n]; Wct[n][k] = (n<64 ? Wmu[k][n] : Wls[k][n-64])

__global__ __launch_bounds__(256) void k_prepw(const float* __restrict__ W1,
                                               const float* __restrict__ Wmu,
                                               const float* __restrict__ Wls,
                                               __half* __restrict__ W1t,
                                               __half* __restrict__ Wct) {
    int i = blockIdx.x * blockDim.x + threadIdx.x;
    if (i < 128 * 128) {
        int n = i >> 7, k = i & 127;
        W1t[i] = __float2half(W1[k * 128 + n]);
        Wct[i] = __float2half(n < 64 ? Wmu[k * 64 + n] : Wls[k * 64 + (n - 64)]);
    }
}

// ---------------- aggregation, XCD-sliced ----------------
// in/out slice-major [8][N][16] fp16, pre-scaled by dinv[src].
// slice = blockIdx % 8 pins each 3.2 MB slice table to one XCD's L2 (round-robin dispatch).
// wave = 8 edge-groups x 8 half2-channels; shfl_xor reduce over edge groups.

__global__ __launch_bounds__(256) void k_aggs(const __half* __restrict__ in, __half* __restrict__ out,
                                              const int* __restrict__ csr_src,
                                              const int* __restrict__ row_start,
                                              const float* __restrict__ dinv) {
    int slice = blockIdx.x & 7;
    int nb = blockIdx.x >> 3;
    const __half* ins = in + (size_t)slice * SLICE;
    __half* outs = out + (size_t)slice * SLICE;
    int wv = threadIdx.x >> 6;
    int lane = threadIdx.x & 63;
    int eg = lane >> 3;              // edge group 0..7
    int c2 = (lane & 7) * 2;         // half offset within 16-ch slice
    int wend = nb * AGG_NPB + AGG_NPB;
    if (wend > N_NODES) wend = N_NODES;
    for (int w = nb * AGG_NPB + wv; w < wend; w += 4) {   // w is wave-uniform
        int beg = row_start[w];
        int cnt = row_start[w + 1] - beg;
        float di = dinv[w];
        float ax = 0.f, ay = 0.f;
        for (int j = 0; j < cnt; j += 16) {
            int e0 = j + eg;
            int e1 = j + 8 + eg;
            if (e1 < cnt) {
                int s0 = csr_src[beg + e0];
                int s1 = csr_src[beg + e1];
                float2 v0 = __half22float2(*(const __half2*)(ins + (size_t)s0 * 16 + c2));
                float2 v1 = __half22float2(*(const __half2*)(ins + (size_t)s1 * 16 + c2));
                ax += v0.x + v1.x;
                ay += v0.y + v1.y;
            } else if (e0 < cnt) {
                int s0 = csr_src[beg + e0];
                float2 v0 = __half22float2(*(const __half2*)(ins + (size_t)s0 * 16 + c2));
                ax += v0.x;
                ay += v0.y;
            }
        }
        // reduce across edge groups (lane bits 3..5)
        ax += __shfl_xor(ax, 8, 64);  ay += __shfl_xor(ay, 8, 64);
        ax += __shfl_xor(ax, 16, 64); ay += __shfl_xor(ay, 16, 64);
        ax += __shfl_xor(ax, 32, 64); ay += __shfl_xor(ay, 32, 64);
        float2 self = __half22float2(*(const __half2*)(ins + (size_t)w * 16 + c2));
        ax = di * (ax + self.x);
        ay = di * (ay + self.y);
        if (eg == 0) *(__half2*)(outs + (size_t)w * 16 + c2) = __floats2half2_rn(ax, ay);
    }
}

// ---------------- GEMM1 (MFMA): H = dinv * relu_normalize(relu(A @ W1 + b1)) ----------------
// A is slice-major [8][N][16]. block = 64 rows (4 waves x 16), N=128 (8 tiles), K=128 (4 steps of 32).
// A-frag: A[m=lane&15][k=quad*8+j] -> slice = kk*2 + (quad>>1), within = (quad&1)*8 + j (no straddle).
// Output H written slice-major for the next k_aggs.

__global__ __launch_bounds__(256) void k_gemm1(const __half* __restrict__ A,
                                               const __half* __restrict__ Wt,
                                               const float* __restrict__ b,
                                               const float* __restrict__ dinv,
                                               __half* __restrict__ H) {
    int t = threadIdx.x;
    int wv = t >> 6;
    int lane = t & 63;
    int m16 = lane & 15;
    int quad = lane >> 4;
    int row = blockIdx.x * 64 + wv * 16 + m16;
    const __half* Abase = A + (size_t)(quad >> 1) * SLICE + (size_t)row * 16 + (quad & 1) * 8;
    floatx4 acc[8];
    #pragma unroll
    for (int tt = 0; tt < 8; tt++) acc[tt] = (floatx4){0.f, 0.f, 0.f, 0.f};
    #pragma unroll
    for (int kk = 0; kk < 4; kk++) {
        half8 a = *(const half8*)(Abase + (size_t)(kk * 2) * SLICE);
        #pragma unroll
        for (int tt = 0; tt < 8; tt++) {
            half8 bf = *(const half8*)(Wt + (size_t)(tt * 16 + m16) * 128 + kk * 32 + quad * 8);
            acc[tt] = __builtin_amdgcn_mfma_f32_16x16x32_f16(a, bf, acc[tt], 0, 0, 0);
        }
    }
    float bias[8];
    #pragma unroll
    for (int tt = 0; tt < 8; tt++) bias[tt] = b[tt * 16 + m16];
    int rbase = blockIdx.x * 64 + wv * 16 + quad * 4;
    #pragma unroll
    for (int r = 0; r < 4; r++) {
        int rw = rbase + r;
        float vv[8];
        float ssq = 0.f;
        #pragma unroll
        for (int tt = 0; tt < 8; tt++) {
            float v = fmaxf(acc[tt][r] + bias[tt], 0.f);
            vv[tt] = v;
            ssq += v * v;
        }
        ssq += __shfl_xor(ssq, 1, 64);
        ssq += __shfl_xor(ssq, 2, 64);
        ssq += __shfl_xor(ssq, 4, 64);
        ssq += __shfl_xor(ssq, 8, 64);
        float s = 1.0f / fmaxf(sqrtf(ssq), 1e-12f);
        if (rw < N_NODES) {
            float sc = s * dinv[rw];  // pre-scale for the next aggregation
            #pragma unroll
            for (int tt = 0; tt < 8; tt++) {
                H[(size_t)tt * SLICE + (size_t)rw * 16 + m16] = __float2half(vv[tt] * sc);
            }
        }
    }
}

// ---------------- GEMM2 (MFMA): out = [ Y2@Wmu+bmu | Y2@Wls+bls ] ----------------
// A slice-major; output row-major f32 (harness layout).

__global__ __launch_bounds__(256) void k_gemm2(const __half* __restrict__ A,
                                               const __half* __restrict__ Wt,
                                               const float* __restrict__ bmu,
                                               const float* __restrict__ bls,
                                               float* __restrict__ out) {
    int t = threadIdx.x;
    int wv = t >> 6;
    int lane = t & 63;
    int m16 = lane & 15;
    int quad = lane >> 4;
    int row = blockIdx.x * 64 + wv * 16 + m16;
    const __half* Abase = A + (size_t)(quad >> 1) * SLICE + (size_t)row * 16 + (quad & 1) * 8;
    floatx4 acc[8];
    #pragma unroll
    for (int tt = 0; tt < 8; tt++) acc[tt] = (floatx4){0.f, 0.f, 0.f, 0.f};
    #pragma unroll
    for (int kk = 0; kk < 4; kk++) {
        half8 a = *(const half8*)(Abase + (size_t)(kk * 2) * SLICE);
        #pragma unroll
        for (int tt = 0; tt < 8; tt++) {
            half8 bf = *(const half8*)(Wt + (size_t)(tt * 16 + m16) * 128 + kk * 32 + quad * 8);
            acc[tt] = __builtin_amdgcn_mfma_f32_16x16x32_f16(a, bf, acc[tt], 0, 0, 0);
        }
    }
    float bias[8];
    #pragma unroll
    for (int tt = 0; tt < 8; tt++)
        bias[tt] = (tt < 4) ? bmu[tt * 16 + m16] : bls[(tt - 4) * 16 + m16];
    int rbase = blockIdx.x * 64 + wv * 16 + quad * 4;
    #pragma unroll
    for (int r = 0; r < 4; r++) {
        int rw = rbase + r;
        if (rw < N_NODES) {
            #pragma unroll
            for (int tt = 0; tt < 4; tt++)
                out[(size_t)rw * 64 + tt * 16 + m16] = acc[tt][r] + bias[tt];
            #pragma unroll
            for (int tt = 4; tt < 8; tt++)
                out[(size_t)N_NODES * 64 + (size_t)rw * 64 + (tt - 4) * 16 + m16] = acc[tt][r] + bias[tt];
        }
    }
}

// ---------------- launch ----------------

extern "C" void kernel_launch(void* const* d_in, const int* in_sizes, int n_in,
                              void* d_out, int out_size, void* d_ws, size_t ws_size,
                              hipStream_t stream) {
    const float* x   = (const float*)d_in[0];
    const int*  eidx = (const int*)d_in[1];
    const float* W1  = (const float*)d_in[2];
    const float* b1  = (const float*)d_in[3];
    const float* Wmu = (const float*)d_in[4];
    const float* bmu = (const float*)d_in[5];
    const float* Wls = (const float*)d_in[6];
    const float* bls = (const float*)d_in[7];
    float* out = (float*)d_out;
    const int* e_src = eidx;
    const int* e_dst = eidx + N_EDGES;

    char* ws = (char*)d_ws;
    size_t off_b = 0;
    auto alloc = [&](size_t n) -> void* {
        void* p = ws + off_b;
        off_b += (n + 255) & ~(size_t)255;
        return p;
    };
    float*  dinv      = (float*)alloc((size_t)N_NODES * sizeof(float));
    int*    row_start = (int*)alloc((size_t)(N_NODES + 1) * sizeof(int));
    int*    hist      = (int*)alloc((size_t)NH * sizeof(int));
    int*    excl2     = (int*)alloc((size_t)NH * sizeof(int));
    int*    bsum2     = (int*)alloc(1024 * sizeof(int));
    int*    boff2     = (int*)alloc(1024 * sizeof(int));
    int*    offs      = (int*)alloc((size_t)NH * sizeof(int));
    int*    csr_src   = (int*)alloc((size_t)N_EDGES * sizeof(int));
    int2*   binned    = (int2*)alloc((size_t)N_EDGES * sizeof(int2));
    __half* W1t       = (__half*)alloc((size_t)128 * 128 * sizeof(__half));
    __half* Wct       = (__half*)alloc((size_t)128 * 128 * sizeof(__half));
    __half* xs        = (__half*)alloc((size_t)N_NODES * IN_CH * sizeof(__half));  // also reused as bufB (y2)
    __half* bufA      = (__half*)alloc((size_t)N_NODES * HID * sizeof(__half));    // y1
    __half* bufH      = (__half*)alloc((size_t)N_NODES * HID * sizeof(__half));    // hs = dinv*h
    alloc(32 * 1024);  // pad for OOB tile reads in last GEMM block
    __half* bufB = xs;  // xs is dead after agg1; reuse for y2

    const int NB_SCAN2 = (NH + SCAN_T - 1) / SCAN_T;  // 98
    const int NGEMM = (N_NODES + 63) / 64;            // 1563

    // weight prep (independent)
    hipLaunchKernelGGL(k_prepw, dim3(64), dim3(256), 0, stream, W1, Wmu, Wls, W1t, Wct);
    // CSR build: hist -> scan -> binscatter -> bucket (produces row_start, dinv, csr_src)
    hipLaunchKernelGGL(k_hist, dim3(BBLK), dim3(256), 0, stream, e_dst, hist);
    hipLaunchKernelGGL(k_scan_local, dim3(NB_SCAN2), dim3(SCAN_T), 0, stream, hist, excl2, bsum2, NH);
    hipLaunchKernelGGL(k_scan_sums, dim3(1), dim3(128), 0, stream, bsum2, boff2, NB_SCAN2);
    hipLaunchKernelGGL(k_scan_add1, dim3((NH + 255) / 256), dim3(256), 0, stream, excl2, boff2, offs, NH);
    hipLaunchKernelGGL(k_binscatter, dim3(BBLK), dim3(256), 0, stream, e_src, e_dst, offs, binned);
    hipLaunchKernelGGL(k_bucket, dim3(NBUCK), dim3(256), 0, stream, binned, offs, row_start, dinv, csr_src);
    // xs = fp16(dinv * x), slice-major  (needs dinv)
    hipLaunchKernelGGL(k_cast_scale, dim3((N_NODES * 32 + 255) / 256), dim3(256), 0, stream, x, dinv, xs);
    // layer 1
    hipLaunchKernelGGL(k_aggs, dim3(8 * AGG_NB), dim3(256), 0, stream, xs, bufA, csr_src, row_start, dinv);
    hipLaunchKernelGGL(k_gemm1, dim3(NGEMM), dim3(256), 0, stream, bufA, W1t, b1, dinv, bufH);
    // shared aggregation for layers 2+3
    hipLaunchKernelGGL(k_aggs, dim3(8 * AGG_NB), dim3(256), 0, stream, bufH, bufB, csr_src, row_start, dinv);
    hipLaunchKernelGGL(k_gemm2, dim3(NGEMM), dim3(256), 0, stream, bufB, Wct, bmu, bls, out);
}

// Round 2
// 394.070 us; speedup vs baseline: 1.6244x; 1.6244x over previous
//
#include <hip/hip_runtime.h>
#include <hip/hip_fp16.h>

#define N_NODES 100000
#define IN_CH 128
#define OUT_CH 64
#define HID 128
#define N_EDGES 1600000

#define NBUCK 196               // dst >> 9, max 99999>>9 = 195
#define BBLK  512               // binning blocks (2 per CU)
#define CHUNK (N_EDGES / BBLK)  // 3125 edges per binning block
#define NH    (NBUCK * BBLK)    // 100352 histogram entries

// slice-major fp16 feature layout: [8 slices][N_NODES][16 ch]
// slice s is 3.2 MB -> fits one XCD's 4 MB L2 when pinned via blockIdx%8
#define SLICE ((size_t)N_NODES * 16)   // halfs per slice
#define AGG_NB (N_NODES / 32)          // 3125 blocks per slice, 32 nodes per block (exact)

typedef _Float16 half8 __attribute__((ext_vector_type(8)));
typedef float floatx4 __attribute__((ext_vector_type(4)));

// ---------------- pass 1: per-(bucket,block) histogram (LDS atomics; fully overwrites hist) ----

__global__ __launch_bounds__(256) void k_hist(const int* __restrict__ dst, int* __restrict__ hist) {
    __shared__ int lh[NBUCK];
    int t = threadIdx.x;
    int blk = blockIdx.x;
    if (t < NBUCK) lh[t] = 0;
    __syncthreads();
    int base = blk * CHUNK;
    for (int i = base + t; i < base + CHUNK; i += 256) {
        atomicAdd(&lh[dst[i] >> 9], 1);
    }
    __syncthreads();
    if (t < NBUCK) hist[t * BBLK + blk] = lh[t];
}

// ---------------- hierarchical exclusive scan (hist only) ----------------

#define SCAN_T 1024
__global__ void k_scan_local(const int* __restrict__ in, int* __restrict__ excl,
                             int* __restrict__ bsum, int n) {
    __shared__ int tmp[SCAN_T];
    int t = threadIdx.x;
    int i = blockIdx.x * SCAN_T + t;
    int v = (i < n) ? in[i] : 0;
    tmp[t] = v;
    __syncthreads();
    for (int off = 1; off < SCAN_T; off <<= 1) {
        int u = (t >= off) ? tmp[t - off] : 0;
        __syncthreads();
        tmp[t] += u;
        __syncthreads();
    }
    if (i < n) excl[i] = tmp[t] - v;
    if (t == SCAN_T - 1) bsum[blockIdx.x] = tmp[t];
}

__global__ void k_scan_sums(const int* __restrict__ bsum, int* __restrict__ boff, int nb) {
    __shared__ int tmp[128];
    int t = threadIdx.x;
    int v = (t < nb) ? bsum[t] : 0;
    tmp[t] = v;
    __syncthreads();
    for (int off = 1; off < 128; off <<= 1) {
        int u = (t >= off) ? tmp[t - off] : 0;
        __syncthreads();
        tmp[t] += u;
        __syncthreads();
    }
    if (t < nb) boff[t] = tmp[t] - v;
}

__global__ void k_scan_add1(const int* __restrict__ excl, const int* __restrict__ boff,
                            int* __restrict__ out, int n) {
    int i = blockIdx.x * blockDim.x + threadIdx.x;
    if (i < n) out[i] = excl[i] + boff[i / SCAN_T];
}

// ---------------- pass 2: scatter edges into bucket-partitioned array ----------------

__global__ __launch_bounds__(256) void k_binscatter(const int* __restrict__ src,
                                                    const int* __restrict__ dst,
                                                    const int* __restrict__ off,
                                                    int2* __restrict__ binned) {
    __shared__ int loff[NBUCK];
    int t = threadIdx.x;
    int blk = blockIdx.x;
    if (t < NBUCK) loff[t] = off[t * BBLK + blk];
    __syncthreads();
    int base = blk * CHUNK;
    for (int i = base + t; i < base + CHUNK; i += 256) {
        int d = dst[i];
        int s = src[i];
        int pos = atomicAdd(&loff[d >> 9], 1);
        binned[pos] = make_int2(s, d);
    }
}

// ---------------- pass 3: per-bucket degree/scan/fill entirely in LDS ----------------
// Produces row_start (with sentinel), dinv, csr_src. Zero global atomics.

__global__ __launch_bounds__(256) void k_bucket(const int2* __restrict__ binned,
                                                const int* __restrict__ off,
                                                int* __restrict__ row_start,
                                                float* __restrict__ dinv,
                                                int* __restrict__ csr_src) {
    __shared__ int cnt[512];
    __shared__ int ps[256];
    __shared__ int cur[512];
    int b = blockIdx.x;
    int t = threadIdx.x;
    int start = off[b * BBLK];
    int end = (b + 1 < NBUCK) ? off[(b + 1) * BBLK] : N_EDGES;
    cnt[t] = 0;
    cnt[t + 256] = 0;
    if (b == NBUCK - 1 && t == 0) row_start[N_NODES] = N_EDGES;  // sentinel
    __syncthreads();
    for (int i = start + t; i < end; i += 256) {
        atomicAdd(&cnt[binned[i].y & 511], 1);
    }
    __syncthreads();
    int a0 = cnt[2 * t], a1 = cnt[2 * t + 1];
    ps[t] = a0 + a1;
    __syncthreads();
    for (int o = 1; o < 256; o <<= 1) {
        int u = (t >= o) ? ps[t - o] : 0;
        __syncthreads();
        ps[t] += u;
        __syncthreads();
    }
    int pe = ps[t] - (a0 + a1);
    int e0 = start + pe;
    int e1 = e0 + a0;
    cur[2 * t] = e0;
    cur[2 * t + 1] = e1;
    int node0 = (b << 9) + 2 * t;
    if (node0 < N_NODES) {
        row_start[node0] = e0;
        dinv[node0] = rsqrtf((float)(a0 + 1));
    }
    if (node0 + 1 < N_NODES) {
        row_start[node0 + 1] = e1;
        dinv[node0 + 1] = rsqrtf((float)(a1 + 1));
    }
    __syncthreads();
    for (int i = start + t; i < end; i += 256) {
        int2 e = binned[i];
        int p = atomicAdd(&cur[e.y & 511], 1);
        csr_src[p] = e.x;
    }
}

// ---------------- cast + pre-scale into SLICE-MAJOR layout ----------------
// xs[slice][node][16] = fp16(dinv[node] * x[node][slice*16 + c])

__global__ __launch_bounds__(256) void k_cast_scale(const float* __restrict__ in,
                                                    const float* __restrict__ dinv,
                                                    __half* __restrict__ out) {
    int i = blockIdx.x * blockDim.x + threadIdx.x;  // over float4 groups, 32 per row
    if (i < N_NODES * 32) {
        float4 v = ((const float4*)in)[i];
        int node = i >> 5, ch4 = i & 31;
        float d = dinv[node];
        // half2 units: slice stride = N_NODES*8, node stride = 8
        size_t o = (size_t)(ch4 >> 2) * (SLICE / 2) + (size_t)node * 8 + (size_t)(ch4 & 3) * 2;
        ((__half2*)out)[o]     = __floats2half2_rn(d * v.x, d * v.y);
        ((__half2*)out)[o + 1] = __floats2half2_rn(d * v.z, d * v.w);
    }
}

// ---------------- weight prep: fp16 transposed (col-major) for MFMA B-fragments --------
// W1t[n][k] = W1[k][n]; Wct[n][k] = (n<64 ? Wmu[k][n] : Wls[k][n-64])

__global__ __launch_bounds__(256) void k_prepw(const float* __restrict__ W1,
                                               const float* __restrict__ Wmu,
                                               const float* __restrict__ Wls,
                                               __half* __restrict__ W1t,
                                               __half* __restrict__ Wct) {
    int i = blockIdx.x * blockDim.x + threadIdx.x;
    if (i < 128 * 128) {
        int n = i >> 7, k = i & 127;
        W1t[i] = __float2half(W1[k * 128 + n]);
        Wct[i] = __float2half(n < 64 ? Wmu[k * 64 + n] : Wls[k * 64 + (n - 64)]);
    }
}

// ---------------- aggregation, XCD-sliced, MLP-8 ----------------
// in/out slice-major [8][N][16] fp16, pre-scaled by dinv[src].
// slice = blockIdx % 8 pins each 3.2 MB slice table to one XCD's L2 (round-robin dispatch).
// wave = 8 node-groups x 8 channel-lanes: each 8-lane group owns ONE node and walks that
// node's edge list with an 8-deep manual unroll -> 8 independent 32B gathers in flight
// per lane (round-0 flight depth, L2-hit latency). No shuffles; coalesced 256B store.

__global__ __launch_bounds__(256) void k_aggs(const __half* __restrict__ in, __half* __restrict__ out,
                                              const int* __restrict__ csr_src,
                                              const int* __restrict__ row_start,
                                              const float* __restrict__ dinv) {
    int slice = blockIdx.x & 7;
    int nb = blockIdx.x >> 3;                 // 0..3124
    const __half* ins = in + (size_t)slice * SLICE;
    __half* outs = out + (size_t)slice * SLICE;
    int wv = threadIdx.x >> 6;
    int lane = threadIdx.x & 63;
    int g = lane >> 3;                        // node sub-group 0..7
    int c2 = (lane & 7) * 2;                  // half offset within 16-ch slice
    int w = nb * 32 + wv * 8 + g;             // this lane's node (uniform within group)
    int beg = row_start[w];
    int cnt = row_start[w + 1] - beg;
    float di = dinv[w];
    float2 self = __half22float2(*(const __half2*)(ins + (size_t)w * 16 + c2));
    float ax = self.x, ay = self.y;
    const int* __restrict__ cp = csr_src + beg;
    int j = 0;
    for (; j + 7 < cnt; j += 8) {
        int s0 = cp[j];
        int s1 = cp[j + 1];
        int s2 = cp[j + 2];
        int s3 = cp[j + 3];
        int s4 = cp[j + 4];
        int s5 = cp[j + 5];
        int s6 = cp[j + 6];
        int s7 = cp[j + 7];
        float2 v0 = __half22float2(*(const __half2*)(ins + (size_t)s0 * 16 + c2));
        float2 v1 = __half22float2(*(const __half2*)(ins + (size_t)s1 * 16 + c2));
        float2 v2 = __half22float2(*(const __half2*)(ins + (size_t)s2 * 16 + c2));
        float2 v3 = __half22float2(*(const __half2*)(ins + (size_t)s3 * 16 + c2));
        float2 v4 = __half22float2(*(const __half2*)(ins + (size_t)s4 * 16 + c2));
        float2 v5 = __half22float2(*(const __half2*)(ins + (size_t)s5 * 16 + c2));
        float2 v6 = __half22float2(*(const __half2*)(ins + (size_t)s6 * 16 + c2));
        float2 v7 = __half22float2(*(const __half2*)(ins + (size_t)s7 * 16 + c2));
        ax += v0.x + v1.x + v2.x + v3.x + v4.x + v5.x + v6.x + v7.x;
        ay += v0.y + v1.y + v2.y + v3.y + v4.y + v5.y + v6.y + v7.y;
    }
    for (; j + 3 < cnt; j += 4) {
        int s0 = cp[j];
        int s1 = cp[j + 1];
        int s2 = cp[j + 2];
        int s3 = cp[j + 3];
        float2 v0 = __half22float2(*(const __half2*)(ins + (size_t)s0 * 16 + c2));
        float2 v1 = __half22float2(*(const __half2*)(ins + (size_t)s1 * 16 + c2));
        float2 v2 = __half22float2(*(const __half2*)(ins + (size_t)s2 * 16 + c2));
        float2 v3 = __half22float2(*(const __half2*)(ins + (size_t)s3 * 16 + c2));
        ax += v0.x + v1.x + v2.x + v3.x;
        ay += v0.y + v1.y + v2.y + v3.y;
    }
    for (; j < cnt; j++) {
        int s0 = cp[j];
        float2 v0 = __half22float2(*(const __half2*)(ins + (size_t)s0 * 16 + c2));
        ax += v0.x;
        ay += v0.y;
    }
    ax *= di;
    ay *= di;
    *(__half2*)(outs + (size_t)w * 16 + c2) = __floats2half2_rn(ax, ay);
}

// ---------------- GEMM1 (MFMA): H = dinv * relu_normalize(relu(A @ W1 + b1)) ----------------
// A is slice-major [8][N][16]. block = 64 rows (4 waves x 16), N=128 (8 tiles), K=128 (4 steps of 32).
// A-frag: A[m=lane&15][k=quad*8+j] -> slice = kk*2 + (quad>>1), within = (quad&1)*8 (no straddle).
// Output H written slice-major for the next k_aggs.

__global__ __launch_bounds__(256) void k_gemm1(const __half* __restrict__ A,
                                               const __half* __restrict__ Wt,
                                               const float* __restrict__ b,
                                               const float* __restrict__ dinv,
                                               __half* __restrict__ H) {
    int t = threadIdx.x;
    int wv = t >> 6;
    int lane = t & 63;
    int m16 = lane & 15;
    int quad = lane >> 4;
    int row = blockIdx.x * 64 + wv * 16 + m16;
    const __half* Abase = A + (size_t)(quad >> 1) * SLICE + (size_t)row * 16 + (quad & 1) * 8;
    floatx4 acc[8];
    #pragma unroll
    for (int tt = 0; tt < 8; tt++) acc[tt] = (floatx4){0.f, 0.f, 0.f, 0.f};
    #pragma unroll
    for (int kk = 0; kk < 4; kk++) {
        half8 a = *(const half8*)(Abase + (size_t)(kk * 2) * SLICE);
        #pragma unroll
        for (int tt = 0; tt < 8; tt++) {
            half8 bf = *(const half8*)(Wt + (size_t)(tt * 16 + m16) * 128 + kk * 32 + quad * 8);
            acc[tt] = __builtin_amdgcn_mfma_f32_16x16x32_f16(a, bf, acc[tt], 0, 0, 0);
        }
    }
    float bias[8];
    #pragma unroll
    for (int tt = 0; tt < 8; tt++) bias[tt] = b[tt * 16 + m16];
    int rbase = blockIdx.x * 64 + wv * 16 + quad * 4;
    #pragma unroll
    for (int r = 0; r < 4; r++) {
        int rw = rbase + r;
        float vv[8];
        float ssq = 0.f;
        #pragma unroll
        for (int tt = 0; tt < 8; tt++) {
            float v = fmaxf(acc[tt][r] + bias[tt], 0.f);
            vv[tt] = v;
            ssq += v * v;
        }
        ssq += __shfl_xor(ssq, 1, 64);
        ssq += __shfl_xor(ssq, 2, 64);
        ssq += __shfl_xor(ssq, 4, 64);
        ssq += __shfl_xor(ssq, 8, 64);
        float s = 1.0f / fmaxf(sqrtf(ssq), 1e-12f);
        if (rw < N_NODES) {
            float sc = s * dinv[rw];  // pre-scale for the next aggregation
            #pragma unroll
            for (int tt = 0; tt < 8; tt++) {
                H[(size_t)tt * SLICE + (size_t)rw * 16 + m16] = __float2half(vv[tt] * sc);
            }
        }
    }
}

// ---------------- GEMM2 (MFMA): out = [ Y2@Wmu+bmu | Y2@Wls+bls ] ----------------
// A slice-major; output row-major f32 (harness layout).

__global__ __launch_bounds__(256) void k_gemm2(const __half* __restrict__ A,
                                               const __half* __restrict__ Wt,
                                               const float* __restrict__ bmu,
                                               const float* __restrict__ bls,
                                               float* __restrict__ out) {
    int t = threadIdx.x;
    int wv = t >> 6;
    int lane = t & 63;
    int m16 = lane & 15;
    int quad = lane >> 4;
    int row = blockIdx.x * 64 + wv * 16 + m16;
    const __half* Abase = A + (size_t)(quad >> 1) * SLICE + (size_t)row * 16 + (quad & 1) * 8;
    floatx4 acc[8];
    #pragma unroll
    for (int tt = 0; tt < 8; tt++) acc[tt] = (floatx4){0.f, 0.f, 0.f, 0.f};
    #pragma unroll
    for (int kk = 0; kk < 4; kk++) {
        half8 a = *(const half8*)(Abase + (size_t)(kk * 2) * SLICE);
        #pragma unroll
        for (int tt = 0; tt < 8; tt++) {
            half8 bf = *(const half8*)(Wt + (size_t)(tt * 16 + m16) * 128 + kk * 32 + quad * 8);
            acc[tt] = __builtin_amdgcn_mfma_f32_16x16x32_f16(a, bf, acc[tt], 0, 0, 0);
        }
    }
    float bias[8];
    #pragma unroll
    for (int tt = 0; tt < 8; tt++)
        bias[tt] = (tt < 4) ? bmu[tt * 16 + m16] : bls[(tt - 4) * 16 + m16];
    int rbase = blockIdx.x * 64 + wv * 16 + quad * 4;
    #pragma unroll
    for (int r = 0; r < 4; r++) {
        int rw = rbase + r;
        if (rw < N_NODES) {
            #pragma unroll
            for (int tt = 0; tt < 4; tt++)
                out[(size_t)rw * 64 + tt * 16 + m16] = acc[tt][r] + bias[tt];
            #pragma unroll
            for (int tt = 4; tt < 8; tt++)
                out[(size_t)N_NODES * 64 + (size_t)rw * 64 + (tt - 4) * 16 + m16] = acc[tt][r] + bias[tt];
        }
    }
}

// ---------------- launch ----------------

extern "C" void kernel_launch(void* const* d_in, const int* in_sizes, int n_in,
                              void* d_out, int out_size, void* d_ws, size_t ws_size,
                              hipStream_t stream) {
    const float* x   = (const float*)d_in[0];
    const int*  eidx = (const int*)d_in[1];
    const float* W1  = (const float*)d_in[2];
    const float* b1  = (const float*)d_in[3];
    const float* Wmu = (const float*)d_in[4];
    const float* bmu = (const float*)d_in[5];
    const float* Wls = (const float*)d_in[6];
    const float* bls = (const float*)d_in[7];
    float* out = (float*)d_out;
    const int* e_src = eidx;
    const int* e_dst = eidx + N_EDGES;

    char* ws = (char*)d_ws;
    size_t off_b = 0;
    auto alloc = [&](size_t n) -> void* {
        void* p = ws + off_b;
        off_b += (n + 255) & ~(size_t)255;
        return p;
    };
    float*  dinv      = (float*)alloc((size_t)N_NODES * sizeof(float));
    int*    row_start = (int*)alloc((size_t)(N_NODES + 1) * sizeof(int));
    int*    hist      = (int*)alloc((size_t)NH * sizeof(int));
    int*    excl2     = (int*)alloc((size_t)NH * sizeof(int));
    int*    bsum2     = (int*)alloc(1024 * sizeof(int));
    int*    boff2     = (int*)alloc(1024 * sizeof(int));
    int*    offs      = (int*)alloc((size_t)NH * sizeof(int));
    int*    csr_src   = (int*)alloc((size_t)N_EDGES * sizeof(int));
    int2*   binned    = (int2*)alloc((size_t)N_EDGES * sizeof(int2));
    __half* W1t       = (__half*)alloc((size_t)128 * 128 * sizeof(__half));
    __half* Wct       = (__half*)alloc((size_t)128 * 128 * sizeof(__half));
    __half* xs        = (__half*)alloc((size_t)N_NODES * IN_CH * sizeof(__half));  // also reused as bufB (y2)
    __half* bufA      = (__half*)alloc((size_t)N_NODES * HID * sizeof(__half));    // y1
    __half* bufH      = (__half*)alloc((size_t)N_NODES * HID * sizeof(__half));    // hs = dinv*h
    alloc(32 * 1024);  // pad for OOB tile reads in last GEMM block
    __half* bufB = xs;  // xs is dead after agg1; reuse for y2

    const int NB_SCAN2 = (NH + SCAN_T - 1) / SCAN_T;  // 98
    const int NGEMM = (N_NODES + 63) / 64;            // 1563

    // weight prep (independent)
    hipLaunchKernelGGL(k_prepw, dim3(64), dim3(256), 0, stream, W1, Wmu, Wls, W1t, Wct);
    // CSR build: hist -> scan -> binscatter -> bucket (produces row_start, dinv, csr_src)
    hipLaunchKernelGGL(k_hist, dim3(BBLK), dim3(256), 0, stream, e_dst, hist);
    hipLaunchKernelGGL(k_scan_local, dim3(NB_SCAN2), dim3(SCAN_T), 0, stream, hist, excl2, bsum2, NH);
    hipLaunchKernelGGL(k_scan_sums, dim3(1), dim3(128), 0, stream, bsum2, boff2, NB_SCAN2);
    hipLaunchKernelGGL(k_scan_add1, dim3((NH + 255) / 256), dim3(256), 0, stream, excl2, boff2, offs, NH);
    hipLaunchKernelGGL(k_binscatter, dim3(BBLK), dim3(256), 0, stream, e_src, e_dst, offs, binned);
    hipLaunchKernelGGL(k_bucket, dim3(NBUCK), dim3(256), 0, stream, binned, offs, row_start, dinv, csr_src);
    // xs = fp16(dinv * x), slice-major  (needs dinv)
    hipLaunchKernelGGL(k_cast_scale, dim3((N_NODES * 32 + 255) / 256), dim3(256), 0, stream, x, dinv, xs);
    // layer 1
    hipLaunchKernelGGL(k_aggs, dim3(8 * AGG_NB), dim3(256), 0, stream, xs, bufA, csr_src, row_start, dinv);
    hipLaunchKernelGGL(k_gemm1, dim3(NGEMM), dim3(256), 0, stream, bufA, W1t, b1, dinv, bufH);
    // shared aggregation for layers 2+3
    hipLaunchKernelGGL(k_aggs, dim3(8 * AGG_NB), dim3(256), 0, stream, bufH, bufB, csr_src, row_start, dinv);
    hipLaunchKernelGGL(k_gemm2, dim3(NGEMM), dim3(256), 0, stream, bufB, Wct, bmu, bls, out);
}

// Round 3
// 387.190 us; speedup vs baseline: 1.6533x; 1.0178x over previous
//
#include <hip/hip_runtime.h>
#include <hip/hip_fp16.h>

#define N_NODES 100000
#define IN_CH 128
#define OUT_CH 64
#define HID 128
#define N_EDGES 1600000

#define NBUCK 196               // dst >> 9, max 99999>>9 = 195
#define BBLK  512               // binning blocks (2 per CU)
#define CHUNK (N_EDGES / BBLK)  // 3125 edges per binning block
#define NH    (NBUCK * BBLK)    // 100352 histogram entries

// slice-major fp16 feature layout: [8 slices][N_NODES][16 ch]
// slice s is 3.2 MB -> fits one XCD's 4 MB L2 when pinned via blockIdx%8
#define SLICE ((size_t)N_NODES * 16)   // halfs per slice
#define AGG_NPB 128                    // nodes per agg block (4 waves x 32 pairs)
#define AGG_NB ((N_NODES + AGG_NPB - 1) / AGG_NPB)  // 782

typedef _Float16 half8 __attribute__((ext_vector_type(8)));
typedef float floatx4 __attribute__((ext_vector_type(4)));

// ---------------- pass 1: per-(bucket,block) histogram (LDS atomics; fully overwrites hist) ----

__global__ __launch_bounds__(256) void k_hist(const int* __restrict__ dst, int* __restrict__ hist) {
    __shared__ int lh[NBUCK];
    int t = threadIdx.x;
    int blk = blockIdx.x;
    if (t < NBUCK) lh[t] = 0;
    __syncthreads();
    int base = blk * CHUNK;
    for (int i = base + t; i < base + CHUNK; i += 256) {
        atomicAdd(&lh[dst[i] >> 9], 1);
    }
    __syncthreads();
    if (t < NBUCK) hist[t * BBLK + blk] = lh[t];
}

// ---------------- hierarchical exclusive scan (hist only) ----------------

#define SCAN_T 1024
__global__ void k_scan_local(const int* __restrict__ in, int* __restrict__ excl,
                             int* __restrict__ bsum, int n) {
    __shared__ int tmp[SCAN_T];
    int t = threadIdx.x;
    int i = blockIdx.x * SCAN_T + t;
    int v = (i < n) ? in[i] : 0;
    tmp[t] = v;
    __syncthreads();
    for (int off = 1; off < SCAN_T; off <<= 1) {
        int u = (t >= off) ? tmp[t - off] : 0;
        __syncthreads();
        tmp[t] += u;
        __syncthreads();
    }
    if (i < n) excl[i] = tmp[t] - v;
    if (t == SCAN_T - 1) bsum[blockIdx.x] = tmp[t];
}

__global__ void k_scan_sums(const int* __restrict__ bsum, int* __restrict__ boff, int nb) {
    __shared__ int tmp[128];
    int t = threadIdx.x;
    int v = (t < nb) ? bsum[t] : 0;
    tmp[t] = v;
    __syncthreads();
    for (int off = 1; off < 128; off <<= 1) {
        int u = (t >= off) ? tmp[t - off] : 0;
        __syncthreads();
        tmp[t] += u;
        __syncthreads();
    }
    if (t < nb) boff[t] = tmp[t] - v;
}

__global__ void k_scan_add1(const int* __restrict__ excl, const int* __restrict__ boff,
                            int* __restrict__ out, int n) {
    int i = blockIdx.x * blockDim.x + threadIdx.x;
    if (i < n) out[i] = excl[i] + boff[i / SCAN_T];
}

// ---------------- pass 2: scatter edges into bucket-partitioned array ----------------

__global__ __launch_bounds__(256) void k_binscatter(const int* __restrict__ src,
                                                    const int* __restrict__ dst,
                                                    const int* __restrict__ off,
                                                    int2* __restrict__ binned) {
    __shared__ int loff[NBUCK];
    int t = threadIdx.x;
    int blk = blockIdx.x;
    if (t < NBUCK) loff[t] = off[t * BBLK + blk];
    __syncthreads();
    int base = blk * CHUNK;
    for (int i = base + t; i < base + CHUNK; i += 256) {
        int d = dst[i];
        int s = src[i];
        int pos = atomicAdd(&loff[d >> 9], 1);
        binned[pos] = make_int2(s, d);
    }
}

// ---------------- pass 3: per-bucket degree/scan/fill entirely in LDS ----------------
// Produces row_start (with sentinel), dinv, csr_src. Zero global atomics.

__global__ __launch_bounds__(256) void k_bucket(const int2* __restrict__ binned,
                                                const int* __restrict__ off,
                                                int* __restrict__ row_start,
                                                float* __restrict__ dinv,
                                                int* __restrict__ csr_src) {
    __shared__ int cnt[512];
    __shared__ int ps[256];
    __shared__ int cur[512];
    int b = blockIdx.x;
    int t = threadIdx.x;
    int start = off[b * BBLK];
    int end = (b + 1 < NBUCK) ? off[(b + 1) * BBLK] : N_EDGES;
    cnt[t] = 0;
    cnt[t + 256] = 0;
    if (b == NBUCK - 1 && t == 0) row_start[N_NODES] = N_EDGES;  // sentinel
    __syncthreads();
    for (int i = start + t; i < end; i += 256) {
        atomicAdd(&cnt[binned[i].y & 511], 1);
    }
    __syncthreads();
    int a0 = cnt[2 * t], a1 = cnt[2 * t + 1];
    ps[t] = a0 + a1;
    __syncthreads();
    for (int o = 1; o < 256; o <<= 1) {
        int u = (t >= o) ? ps[t - o] : 0;
        __syncthreads();
        ps[t] += u;
        __syncthreads();
    }
    int pe = ps[t] - (a0 + a1);
    int e0 = start + pe;
    int e1 = e0 + a0;
    cur[2 * t] = e0;
    cur[2 * t + 1] = e1;
    int node0 = (b << 9) + 2 * t;
    if (node0 < N_NODES) {
        row_start[node0] = e0;
        dinv[node0] = rsqrtf((float)(a0 + 1));
    }
    if (node0 + 1 < N_NODES) {
        row_start[node0 + 1] = e1;
        dinv[node0 + 1] = rsqrtf((float)(a1 + 1));
    }
    __syncthreads();
    for (int i = start + t; i < end; i += 256) {
        int2 e = binned[i];
        int p = atomicAdd(&cur[e.y & 511], 1);
        csr_src[p] = e.x;
    }
}

// ---------------- cast + pre-scale into SLICE-MAJOR layout, + folded weight prep --------
// blocks < 12500: xs[slice][node][16] = fp16(dinv[node] * x[node][slice*16+c])
// blocks >= 12500: W1t[n][k] = W1[k][n]; Wct[n][k] = (n<64 ? Wmu[k][n] : Wls[k][n-64])

__global__ __launch_bounds__(256) void k_cast_prep(const float* __restrict__ in,
                                                   const float* __restrict__ dinv,
                                                   __half* __restrict__ out,
                                                   const float* __restrict__ W1,
                                                   const float* __restrict__ Wmu,
                                                   const float* __restrict__ Wls,
                                                   __half* __restrict__ W1t,
                                                   __half* __restrict__ Wct) {
    int blk = blockIdx.x;
    int t = threadIdx.x;
    if (blk >= 12500) {  // weight prep tail blocks (64 blocks x 256 = 16384)
        int i = (blk - 12500) * 256 + t;
        if (i < 128 * 128) {
            int n = i >> 7, k = i & 127;
            W1t[i] = __float2half(W1[k * 128 + n]);
            Wct[i] = __float2half(n < 64 ? Wmu[k * 64 + n] : Wls[k * 64 + (n - 64)]);
        }
        return;
    }
    int i = blk * 256 + t;  // over float4 groups, 32 per row; 12500*256 = N_NODES*32 exact
    float4 v = ((const float4*)in)[i];
    int node = i >> 5, ch4 = i & 31;
    float d = dinv[node];
    // half2 units: slice stride = N_NODES*8, node stride = 8
    size_t o = (size_t)(ch4 >> 2) * (SLICE / 2) + (size_t)node * 8 + (size_t)(ch4 & 3) * 2;
    ((__half2*)out)[o]     = __floats2half2_rn(d * v.x, d * v.y);
    ((__half2*)out)[o + 1] = __floats2half2_rn(d * v.z, d * v.w);
}

// ---------------- aggregation, XCD-sliced, lane-pair half8 ----------------
// in/out slice-major [8][N][16] fp16, pre-scaled by dinv[src].
// slice = blockIdx % 8 pins each 3.2 MB slice table to one XCD's L2 (proven: FETCH ~= compulsory).
// wave = 32 lane-pairs; each pair owns ONE node, each lane loads half8 (16 B, one half of the
// 32-B row-slice). One vmem inst covers 32 edges (32 x 32-B clusters) vs 8 before; unroll-8
// keeps 256 clusters in flight per wave. Lane-local accumulate, zero shuffles, 1-KB wave store.

__global__ __launch_bounds__(256) void k_aggs(const __half* __restrict__ in, __half* __restrict__ out,
                                              const int* __restrict__ csr_src,
                                              const int* __restrict__ row_start,
                                              const float* __restrict__ dinv) {
    int slice = blockIdx.x & 7;
    int nb = blockIdx.x >> 3;                 // 0..781
    const __half* ins = in + (size_t)slice * SLICE;
    __half* outs = out + (size_t)slice * SLICE;
    int t = threadIdx.x;
    int lane = t & 63;
    int w = nb * AGG_NPB + (t >> 6) * 32 + (lane >> 1);  // this pair's node
    int hb = (lane & 1) * 8;                  // half offset (halfs) within 16-ch slice row
    if (w >= N_NODES) return;
    int beg = row_start[w];
    int cnt = row_start[w + 1] - beg;
    float di = dinv[w];
    const int* __restrict__ cp = csr_src + beg;
    half8 sv = *(const half8*)(ins + (size_t)w * 16 + hb);  // self term
    float a0 = (float)sv[0], a1 = (float)sv[1], a2 = (float)sv[2], a3 = (float)sv[3];
    float a4 = (float)sv[4], a5 = (float)sv[5], a6 = (float)sv[6], a7 = (float)sv[7];
    int j = 0;
    for (; j + 7 < cnt; j += 8) {
        int s0 = cp[j];
        int s1 = cp[j + 1];
        int s2 = cp[j + 2];
        int s3 = cp[j + 3];
        int s4 = cp[j + 4];
        int s5 = cp[j + 5];
        int s6 = cp[j + 6];
        int s7 = cp[j + 7];
        half8 v0 = *(const half8*)(ins + (size_t)s0 * 16 + hb);
        half8 v1 = *(const half8*)(ins + (size_t)s1 * 16 + hb);
        half8 v2 = *(const half8*)(ins + (size_t)s2 * 16 + hb);
        half8 v3 = *(const half8*)(ins + (size_t)s3 * 16 + hb);
        half8 v4 = *(const half8*)(ins + (size_t)s4 * 16 + hb);
        half8 v5 = *(const half8*)(ins + (size_t)s5 * 16 + hb);
        half8 v6 = *(const half8*)(ins + (size_t)s6 * 16 + hb);
        half8 v7 = *(const half8*)(ins + (size_t)s7 * 16 + hb);
        a0 += (float)v0[0] + (float)v1[0] + (float)v2[0] + (float)v3[0] + (float)v4[0] + (float)v5[0] + (float)v6[0] + (float)v7[0];
        a1 += (float)v0[1] + (float)v1[1] + (float)v2[1] + (float)v3[1] + (float)v4[1] + (float)v5[1] + (float)v6[1] + (float)v7[1];
        a2 += (float)v0[2] + (float)v1[2] + (float)v2[2] + (float)v3[2] + (float)v4[2] + (float)v5[2] + (float)v6[2] + (float)v7[2];
        a3 += (float)v0[3] + (float)v1[3] + (float)v2[3] + (float)v3[3] + (float)v4[3] + (float)v5[3] + (float)v6[3] + (float)v7[3];
        a4 += (float)v0[4] + (float)v1[4] + (float)v2[4] + (float)v3[4] + (float)v4[4] + (float)v5[4] + (float)v6[4] + (float)v7[4];
        a5 += (float)v0[5] + (float)v1[5] + (float)v2[5] + (float)v3[5] + (float)v4[5] + (float)v5[5] + (float)v6[5] + (float)v7[5];
        a6 += (float)v0[6] + (float)v1[6] + (float)v2[6] + (float)v3[6] + (float)v4[6] + (float)v5[6] + (float)v6[6] + (float)v7[6];
        a7 += (float)v0[7] + (float)v1[7] + (float)v2[7] + (float)v3[7] + (float)v4[7] + (float)v5[7] + (float)v6[7] + (float)v7[7];
    }
    for (; j + 1 < cnt; j += 2) {
        int s0 = cp[j];
        int s1 = cp[j + 1];
        half8 v0 = *(const half8*)(ins + (size_t)s0 * 16 + hb);
        half8 v1 = *(const half8*)(ins + (size_t)s1 * 16 + hb);
        a0 += (float)v0[0] + (float)v1[0];
        a1 += (float)v0[1] + (float)v1[1];
        a2 += (float)v0[2] + (float)v1[2];
        a3 += (float)v0[3] + (float)v1[3];
        a4 += (float)v0[4] + (float)v1[4];
        a5 += (float)v0[5] + (float)v1[5];
        a6 += (float)v0[6] + (float)v1[6];
        a7 += (float)v0[7] + (float)v1[7];
    }
    if (j < cnt) {
        int s0 = cp[j];
        half8 v0 = *(const half8*)(ins + (size_t)s0 * 16 + hb);
        a0 += (float)v0[0];
        a1 += (float)v0[1];
        a2 += (float)v0[2];
        a3 += (float)v0[3];
        a4 += (float)v0[4];
        a5 += (float)v0[5];
        a6 += (float)v0[6];
        a7 += (float)v0[7];
    }
    half8 o;
    o[0] = (_Float16)(di * a0);
    o[1] = (_Float16)(di * a1);
    o[2] = (_Float16)(di * a2);
    o[3] = (_Float16)(di * a3);
    o[4] = (_Float16)(di * a4);
    o[5] = (_Float16)(di * a5);
    o[6] = (_Float16)(di * a6);
    o[7] = (_Float16)(di * a7);
    *(half8*)(outs + (size_t)w * 16 + hb) = o;
}

// ---------------- GEMM1 (MFMA): H = dinv * relu_normalize(relu(A @ W1 + b1)) ----------------
// A is slice-major [8][N][16]. block = 64 rows (4 waves x 16), N=128 (8 tiles), K=128 (4 steps of 32).
// A-frag: A[m=lane&15][k=quad*8+j] -> slice = kk*2 + (quad>>1), within = (quad&1)*8 (no straddle).
// Quads 0/1 jointly cover 16 complete 32-B rows of slice kk*2 (512 contiguous B) -> line-efficient.
// Output H written slice-major for the next k_aggs.

__global__ __launch_bounds__(256) void k_gemm1(const __half* __restrict__ A,
                                               const __half* __restrict__ Wt,
                                               const float* __restrict__ b,
                                               const float* __restrict__ dinv,
                                               __half* __restrict__ H) {
    int t = threadIdx.x;
    int wv = t >> 6;
    int lane = t & 63;
    int m16 = lane & 15;
    int quad = lane >> 4;
    int row = blockIdx.x * 64 + wv * 16 + m16;
    const __half* Abase = A + (size_t)(quad >> 1) * SLICE + (size_t)row * 16 + (quad & 1) * 8;
    floatx4 acc[8];
    #pragma unroll
    for (int tt = 0; tt < 8; tt++) acc[tt] = (floatx4){0.f, 0.f, 0.f, 0.f};
    #pragma unroll
    for (int kk = 0; kk < 4; kk++) {
        half8 a = *(const half8*)(Abase + (size_t)(kk * 2) * SLICE);
        #pragma unroll
        for (int tt = 0; tt < 8; tt++) {
            half8 bf = *(const half8*)(Wt + (size_t)(tt * 16 + m16) * 128 + kk * 32 + quad * 8);
            acc[tt] = __builtin_amdgcn_mfma_f32_16x16x32_f16(a, bf, acc[tt], 0, 0, 0);
        }
    }
    float bias[8];
    #pragma unroll
    for (int tt = 0; tt < 8; tt++) bias[tt] = b[tt * 16 + m16];
    int rbase = blockIdx.x * 64 + wv * 16 + quad * 4;
    #pragma unroll
    for (int r = 0; r < 4; r++) {
        int rw = rbase + r;
        float vv[8];
        float ssq = 0.f;
        #pragma unroll
        for (int tt = 0; tt < 8; tt++) {
            float v = fmaxf(acc[tt][r] + bias[tt], 0.f);
            vv[tt] = v;
            ssq += v * v;
        }
        ssq += __shfl_xor(ssq, 1, 64);
        ssq += __shfl_xor(ssq, 2, 64);
        ssq += __shfl_xor(ssq, 4, 64);
        ssq += __shfl_xor(ssq, 8, 64);
        float s = 1.0f / fmaxf(sqrtf(ssq), 1e-12f);
        if (rw < N_NODES) {
            float sc = s * dinv[rw];  // pre-scale for the next aggregation
            #pragma unroll
            for (int tt = 0; tt < 8; tt++) {
                H[(size_t)tt * SLICE + (size_t)rw * 16 + m16] = __float2half(vv[tt] * sc);
            }
        }
    }
}

// ---------------- GEMM2 (MFMA): out = [ Y2@Wmu+bmu | Y2@Wls+bls ] ----------------
// A slice-major; output row-major f32 (harness layout).

__global__ __launch_bounds__(256) void k_gemm2(const __half* __restrict__ A,
                                               const __half* __restrict__ Wt,
                                               const float* __restrict__ bmu,
                                               const float* __restrict__ bls,
                                               float* __restrict__ out) {
    int t = threadIdx.x;
    int wv = t >> 6;
    int lane = t & 63;
    int m16 = lane & 15;
    int quad = lane >> 4;
    int row = blockIdx.x * 64 + wv * 16 + m16;
    const __half* Abase = A + (size_t)(quad >> 1) * SLICE + (size_t)row * 16 + (quad & 1) * 8;
    floatx4 acc[8];
    #pragma unroll
    for (int tt = 0; tt < 8; tt++) acc[tt] = (floatx4){0.f, 0.f, 0.f, 0.f};
    #pragma unroll
    for (int kk = 0; kk < 4; kk++) {
        half8 a = *(const half8*)(Abase + (size_t)(kk * 2) * SLICE);
        #pragma unroll
        for (int tt = 0; tt < 8; tt++) {
            half8 bf = *(const half8*)(Wt + (size_t)(tt * 16 + m16) * 128 + kk * 32 + quad * 8);
            acc[tt] = __builtin_amdgcn_mfma_f32_16x16x32_f16(a, bf, acc[tt], 0, 0, 0);
        }
    }
    float bias[8];
    #pragma unroll
    for (int tt = 0; tt < 8; tt++)
        bias[tt] = (tt < 4) ? bmu[tt * 16 + m16] : bls[(tt - 4) * 16 + m16];
    int rbase = blockIdx.x * 64 + wv * 16 + quad * 4;
    #pragma unroll
    for (int r = 0; r < 4; r++) {
        int rw = rbase + r;
        if (rw < N_NODES) {
            #pragma unroll
            for (int tt = 0; tt < 4; tt++)
                out[(size_t)rw * 64 + tt * 16 + m16] = acc[tt][r] + bias[tt];
            #pragma unroll
            for (int tt = 4; tt < 8; tt++)
                out[(size_t)N_NODES * 64 + (size_t)rw * 64 + (tt - 4) * 16 + m16] = acc[tt][r] + bias[tt];
        }
    }
}

// ---------------- launch ----------------

extern "C" void kernel_launch(void* const* d_in, const int* in_sizes, int n_in,
                              void* d_out, int out_size, void* d_ws, size_t ws_size,
                              hipStream_t stream) {
    const float* x   = (const float*)d_in[0];
    const int*  eidx = (const int*)d_in[1];
    const float* W1  = (const float*)d_in[2];
    const float* b1  = (const float*)d_in[3];
    const float* Wmu = (const float*)d_in[4];
    const float* bmu = (const float*)d_in[5];
    const float* Wls = (const float*)d_in[6];
    const float* bls = (const float*)d_in[7];
    float* out = (float*)d_out;
    const int* e_src = eidx;
    const int* e_dst = eidx + N_EDGES;

    char* ws = (char*)d_ws;
    size_t off_b = 0;
    auto alloc = [&](size_t n) -> void* {
        void* p = ws + off_b;
        off_b += (n + 255) & ~(size_t)255;
        return p;
    };
    float*  dinv      = (float*)alloc((size_t)N_NODES * sizeof(float));
    int*    row_start = (int*)alloc((size_t)(N_NODES + 1) * sizeof(int));
    int*    hist      = (int*)alloc((size_t)NH * sizeof(int));
    int*    excl2     = (int*)alloc((size_t)NH * sizeof(int));
    int*    bsum2     = (int*)alloc(1024 * sizeof(int));
    int*    boff2     = (int*)alloc(1024 * sizeof(int));
    int*    offs      = (int*)alloc((size_t)NH * sizeof(int));
    int*    csr_src   = (int*)alloc((size_t)N_EDGES * sizeof(int));
    int2*   binned    = (int2*)alloc((size_t)N_EDGES * sizeof(int2));
    __half* W1t       = (__half*)alloc((size_t)128 * 128 * sizeof(__half));
    __half* Wct       = (__half*)alloc((size_t)128 * 128 * sizeof(__half));
    __half* xs        = (__half*)alloc((size_t)N_NODES * IN_CH * sizeof(__half));  // also reused as bufB (y2)
    __half* bufA      = (__half*)alloc((size_t)N_NODES * HID * sizeof(__half));    // y1
    __half* bufH      = (__half*)alloc((size_t)N_NODES * HID * sizeof(__half));    // hs = dinv*h
    alloc(32 * 1024);  // pad for OOB tile reads in last GEMM block
    __half* bufB = xs;  // xs is dead after agg1; reuse for y2

    const int NB_SCAN2 = (NH + SCAN_T - 1) / SCAN_T;  // 98
    const int NGEMM = (N_NODES + 63) / 64;            // 1563

    // CSR build: hist -> scan -> binscatter -> bucket (produces row_start, dinv, csr_src)
    hipLaunchKernelGGL(k_hist, dim3(BBLK), dim3(256), 0, stream, e_dst, hist);
    hipLaunchKernelGGL(k_scan_local, dim3(NB_SCAN2), dim3(SCAN_T), 0, stream, hist, excl2, bsum2, NH);
    hipLaunchKernelGGL(k_scan_sums, dim3(1), dim3(128), 0, stream, bsum2, boff2, NB_SCAN2);
    hipLaunchKernelGGL(k_scan_add1, dim3((NH + 255) / 256), dim3(256), 0, stream, excl2, boff2, offs, NH);
    hipLaunchKernelGGL(k_binscatter, dim3(BBLK), dim3(256), 0, stream, e_src, e_dst, offs, binned);
    hipLaunchKernelGGL(k_bucket, dim3(NBUCK), dim3(256), 0, stream, binned, offs, row_start, dinv, csr_src);
    // xs = fp16(dinv * x) slice-major, + folded weight prep (needs dinv)
    hipLaunchKernelGGL(k_cast_prep, dim3(12500 + 64), dim3(256), 0, stream, x, dinv, xs,
                       W1, Wmu, Wls, W1t, Wct);
    // layer 1
    hipLaunchKernelGGL(k_aggs, dim3(8 * AGG_NB), dim3(256), 0, stream, xs, bufA, csr_src, row_start, dinv);
    hipLaunchKernelGGL(k_gemm1, dim3(NGEMM), dim3(256), 0, stream, bufA, W1t, b1, dinv, bufH);
    // shared aggregation for layers 2+3
    hipLaunchKernelGGL(k_aggs, dim3(8 * AGG_NB), dim3(256), 0, stream, bufH, bufB, csr_src, row_start, dinv);
    hipLaunchKernelGGL(k_gemm2, dim3(NGEMM), dim3(256), 0, stream, bufB, Wct, bmu, bls, out);
}